// Round 1
// baseline (593.565 us; speedup 1.0000x reference)
//
#include <hip/hip_runtime.h>
#include <hip/hip_bf16.h>

constexpr int N_NODES = 50000;
constexpr int N_EDGES = 800000;
constexpr int ET      = N_EDGES + N_NODES;   // edges incl. self loops
constexpr int HC      = 256;                 // heads * dim_h (layer 1)
constexpr int NCLS    = 10;
constexpr float NEG   = 0.2f;

// ---------------------------- CSR build ----------------------------

__global__ void k_zero_int(int* __restrict__ p, int n) {
  int i = blockIdx.x * 256 + threadIdx.x;
  if (i < n) p[i] = 0;
}

__global__ void k_hist(const int* __restrict__ ei, int* __restrict__ counts) {
  int e = blockIdx.x * 256 + threadIdx.x;
  if (e >= ET) return;
  int d = (e < N_EDGES) ? ei[N_EDGES + e] : (e - N_EDGES);
  atomicAdd(&counts[d], 1);
}

// block of 256 threads scans 1024 elements (inclusive), writes offsets[idx+1]
__global__ __launch_bounds__(256) void k_scan1(const int* __restrict__ counts,
                                               int* __restrict__ offsets,
                                               int* __restrict__ bsums) {
  __shared__ int sd[256];
  int t = threadIdx.x;
  int base = blockIdx.x * 1024 + t * 4;
  int v[4];
#pragma unroll
  for (int i = 0; i < 4; ++i) {
    int idx = base + i;
    v[i] = (idx < N_NODES) ? counts[idx] : 0;
  }
  int tsum = v[0] + v[1] + v[2] + v[3];
  sd[t] = tsum;
  __syncthreads();
  for (int off = 1; off < 256; off <<= 1) {
    int x = (t >= off) ? sd[t - off] : 0;
    __syncthreads();
    sd[t] += x;
    __syncthreads();
  }
  int run = sd[t] - tsum;  // exclusive prefix of this thread
#pragma unroll
  for (int i = 0; i < 4; ++i) {
    run += v[i];
    int idx = base + i;
    if (idx < N_NODES) offsets[idx + 1] = run;
  }
  if (t == 255) bsums[blockIdx.x] = sd[255];
}

__global__ __launch_bounds__(256) void k_scan2(int* __restrict__ bsums, int nb) {
  __shared__ int sd[256];
  int t = threadIdx.x;
  int v = (t < nb) ? bsums[t] : 0;
  sd[t] = v;
  __syncthreads();
  for (int off = 1; off < 256; off <<= 1) {
    int x = (t >= off) ? sd[t - off] : 0;
    __syncthreads();
    sd[t] += x;
    __syncthreads();
  }
  if (t < nb) bsums[t] = sd[t] - v;  // exclusive
}

__global__ void k_scan3(const int* __restrict__ bsums, int* __restrict__ offsets) {
  int i = blockIdx.x * 256 + threadIdx.x;
  if (i < N_NODES) offsets[i + 1] += bsums[i >> 10];
  if (i == 0) offsets[0] = 0;
}

__global__ void k_copy_int(const int* __restrict__ a, int* __restrict__ b, int n) {
  int i = blockIdx.x * 256 + threadIdx.x;
  if (i < n) b[i] = a[i];
}

__global__ void k_scatter(const int* __restrict__ ei, int* __restrict__ cursor,
                          int* __restrict__ srcs) {
  int e = blockIdx.x * 256 + threadIdx.x;
  if (e >= ET) return;
  int s, d;
  if (e < N_EDGES) { s = ei[e]; d = ei[N_EDGES + e]; }
  else             { s = e - N_EDGES; d = s; }
  int pos = atomicAdd(&cursor[d], 1);
  srcs[pos] = s;
}

// ------------------- layer-1 fused GEMM: xl1 = x@Wl, xr1 = x@Wr -------------
// C viewed as [N, 512]; col tile 0..3 -> Wl, 4..7 -> Wr. BM=BN=64, BK=16.
__global__ __launch_bounds__(256) void k_gemm1(const float* __restrict__ x,
                                               const float* __restrict__ Wl,
                                               const float* __restrict__ Wr,
                                               float* __restrict__ xl,
                                               float* __restrict__ xr) {
  __shared__ float As[16][64];
  __shared__ float Bs[16][64];
  int row0 = blockIdx.x * 64;
  int col0 = blockIdx.y * 64;                 // 0..511
  const float* B = (col0 < 256) ? Wl : Wr;
  float* Cout    = (col0 < 256) ? xl : xr;
  int bcol = col0 & 255;
  int t = threadIdx.x;
  int tx = t & 15, ty = t >> 4;
  float acc[4][4] = {};
  for (int kk = 0; kk < 256; kk += 16) {
    {  // A tile 64x16
      int r = t >> 2;
      int c = (t & 3) * 4;
      int gr = row0 + r;
      float4 v = (gr < N_NODES) ? *(const float4*)&x[gr * 256 + kk + c]
                                : make_float4(0.f, 0.f, 0.f, 0.f);
      As[c + 0][r] = v.x; As[c + 1][r] = v.y; As[c + 2][r] = v.z; As[c + 3][r] = v.w;
    }
    {  // B tile 16x64
      int r = t >> 4;
      int c = (t & 15) * 4;
      float4 v = *(const float4*)&B[(kk + r) * 256 + bcol + c];
      *(float4*)&Bs[r][c] = v;
    }
    __syncthreads();
#pragma unroll
    for (int k = 0; k < 16; ++k) {
      float4 a = *(const float4*)&As[k][ty * 4];
      float4 b = *(const float4*)&Bs[k][tx * 4];
      float av[4] = {a.x, a.y, a.z, a.w};
      float bv[4] = {b.x, b.y, b.z, b.w};
#pragma unroll
      for (int i = 0; i < 4; ++i)
#pragma unroll
        for (int j = 0; j < 4; ++j) acc[i][j] += av[i] * bv[j];
    }
    __syncthreads();
  }
#pragma unroll
  for (int i = 0; i < 4; ++i) {
    int gr = row0 + ty * 4 + i;
    if (gr < N_NODES) {
      float4 v = make_float4(acc[i][0], acc[i][1], acc[i][2], acc[i][3]);
      *(float4*)&Cout[gr * 256 + bcol + tx * 4] = v;
    }
  }
}

// ---------------- layer-1 online-softmax aggregation --------------------
// one wave per dst node; lane owns channels 4l..4l+3 (head = lane>>4).
// writes h = relu(out + b1). hout may alias xr (row n read before written).
__global__ __launch_bounds__(256) void k_gat1(const float* __restrict__ xl,
                                              const float* __restrict__ xr,
                                              const float* __restrict__ att,
                                              const float* __restrict__ b1,
                                              const int* __restrict__ offsets,
                                              const int* __restrict__ srcs,
                                              float* __restrict__ hout) {
  int wave = threadIdx.x >> 6;
  int lane = threadIdx.x & 63;
  int n = blockIdx.x * 4 + wave;
  if (n >= N_NODES) return;
  int c0 = lane * 4;
  float4 attv = *(const float4*)&att[c0];
  float4 xrv  = *(const float4*)&xr[(size_t)n * 256 + c0];
  float m = -__builtin_inff();
  float denom = 0.f;
  float a0 = 0.f, a1 = 0.f, a2 = 0.f, a3 = 0.f;
  int jb = offsets[n], je = offsets[n + 1];
  for (int j = jb; j < je; ++j) {
    int s = srcs[j];
    float4 xlv = *(const float4*)&xl[(size_t)s * 256 + c0];
    float e0 = xlv.x + xrv.x; e0 = e0 > 0.f ? e0 : NEG * e0;
    float e1 = xlv.y + xrv.y; e1 = e1 > 0.f ? e1 : NEG * e1;
    float e2 = xlv.z + xrv.z; e2 = e2 > 0.f ? e2 : NEG * e2;
    float e3 = xlv.w + xrv.w; e3 = e3 > 0.f ? e3 : NEG * e3;
    float p = attv.x * e0 + attv.y * e1 + attv.z * e2 + attv.w * e3;
    p += __shfl_xor(p, 1);
    p += __shfl_xor(p, 2);
    p += __shfl_xor(p, 4);
    p += __shfl_xor(p, 8);               // head-group (16 lanes) total
    float mn = fmaxf(m, p);
    float corr = __expf(m - mn);
    float w    = __expf(p - mn);
    denom = denom * corr + w;
    a0 = a0 * corr + w * xlv.x;
    a1 = a1 * corr + w * xlv.y;
    a2 = a2 * corr + w * xlv.z;
    a3 = a3 * corr + w * xlv.w;
    m = mn;
  }
  float inv = 1.0f / denom;
  float4 bv = *(const float4*)&b1[c0];
  float4 o;
  o.x = fmaxf(a0 * inv + bv.x, 0.f);
  o.y = fmaxf(a1 * inv + bv.y, 0.f);
  o.z = fmaxf(a2 * inv + bv.z, 0.f);
  o.w = fmaxf(a3 * inv + bv.w, 0.f);
  *(float4*)&hout[(size_t)n * 256 + c0] = o;
}

// ------------- layer-2 GEMM: xl2 = h@Wl2, xr2 = h@Wr2 ([256,10] each) -------
__global__ __launch_bounds__(256) void k_gemm2(const float* __restrict__ h,
                                               const float* __restrict__ Wl,
                                               const float* __restrict__ Wr,
                                               float* __restrict__ xl2,
                                               float* __restrict__ xr2) {
  __shared__ float Ws[256 * 20];   // [k][c] c<10: Wl col c ; c>=10: Wr col c-10
  __shared__ float hs[32][256];
  int t = threadIdx.x;
  for (int i = t; i < 256 * 10; i += 256) {
    int kk = i / 10, c = i % 10;
    Ws[kk * 20 + c]      = Wl[i];
    Ws[kk * 20 + 10 + c] = Wr[i];
  }
  int row0 = blockIdx.x * 32;
  for (int i = t * 4; i < 32 * 256; i += 256 * 4) {
    int r = i >> 8, c = i & 255;
    int gr = row0 + r;
    float4 v = (gr < N_NODES) ? *(const float4*)&h[(size_t)gr * 256 + c]
                              : make_float4(0.f, 0.f, 0.f, 0.f);
    *(float4*)&hs[r][c] = v;
  }
  __syncthreads();
  int c = t & 31;
  int rbase = t >> 5;
  if (c < 20) {
#pragma unroll
    for (int it = 0; it < 4; ++it) {
      int r = rbase + it * 8;
      int gr = row0 + r;
      if (gr < N_NODES) {
        float acc = 0.f;
#pragma unroll 8
        for (int k = 0; k < 256; ++k) acc += hs[r][k] * Ws[k * 20 + c];
        if (c < 10) xl2[gr * 10 + c] = acc;
        else        xr2[gr * 10 + (c - 10)] = acc;
      }
    }
  }
}

// ---------------- layer-2 aggregation: 4 edge-groups of 16 lanes ------------
__global__ __launch_bounds__(256) void k_gat2(const float* __restrict__ xl2,
                                              const float* __restrict__ xr2,
                                              const float* __restrict__ att2,
                                              const float* __restrict__ b2,
                                              const int* __restrict__ offsets,
                                              const int* __restrict__ srcs,
                                              float* __restrict__ out) {
  int wave = threadIdx.x >> 6;
  int lane = threadIdx.x & 63;
  int n = blockIdx.x * 4 + wave;
  if (n >= N_NODES) return;
  int g = lane >> 4;       // edge group 0..3
  int k = lane & 15;       // channel, active k<10
  bool act = k < NCLS;
  float attk = act ? att2[k] : 0.f;
  float xrk  = act ? xr2[n * NCLS + k] : 0.f;
  float m = -__builtin_inff();
  float denom = 0.f, acc = 0.f;
  int jb = offsets[n], je = offsets[n + 1];
  for (int j = jb + g; j < je; j += 4) {
    int s = srcs[j];
    float xlv = act ? xl2[s * NCLS + k] : 0.f;
    float e = xlv + xrk; e = e > 0.f ? e : NEG * e;
    float p = attk * e;
    p += __shfl_xor(p, 1);
    p += __shfl_xor(p, 2);
    p += __shfl_xor(p, 4);
    p += __shfl_xor(p, 8);
    float mn = fmaxf(m, p);
    float corr = __expf(m - mn);
    float w    = __expf(p - mn);
    denom = denom * corr + w;
    acc   = acc * corr + w * xlv;
    m = mn;
  }
  // merge the 4 groups (flash-style)
  float mg = fmaxf(m, __shfl_xor(m, 16));
  mg = fmaxf(mg, __shfl_xor(mg, 32));
  float f = __expf(m - mg);        // exp(-inf)=0 for empty groups
  float d = denom * f;
  d += __shfl_xor(d, 16);
  d += __shfl_xor(d, 32);
  float a = acc * f;
  a += __shfl_xor(a, 16);
  a += __shfl_xor(a, 32);
  if (act && g == 0) out[n * NCLS + k] = a / d + b2[k];
}

// ----------------------------------------------------------------------------

extern "C" void kernel_launch(void* const* d_in, const int* in_sizes, int n_in,
                              void* d_out, int out_size, void* d_ws, size_t ws_size,
                              hipStream_t stream) {
  const float* x    = (const float*)d_in[0];
  const int*   ei   = (const int*)d_in[1];
  const float* Wl1  = (const float*)d_in[2];
  const float* Wr1  = (const float*)d_in[3];
  const float* att1 = (const float*)d_in[4];
  const float* b1   = (const float*)d_in[5];
  const float* Wl2  = (const float*)d_in[6];
  const float* Wr2  = (const float*)d_in[7];
  const float* att2 = (const float*)d_in[8];
  const float* b2   = (const float*)d_in[9];
  float* out = (float*)d_out;

  // workspace layout: ints first, then float region (64-int aligned)
  int* offsets = (int*)d_ws;                 // N+1
  int* cursor  = offsets + (N_NODES + 1);    // N (doubles as counts)
  int* bsums   = cursor + N_NODES;           // 256
  int* srcs    = bsums + 256;                // ET
  size_t int_count = (size_t)(N_NODES + 1) + N_NODES + 256 + ET;
  size_t foff = (int_count + 63) & ~(size_t)63;
  float* xl1 = (float*)d_ws + foff;                    // N*256
  float* xr1 = xl1 + (size_t)N_NODES * HC;             // N*256
  float* hb  = xr1;                                    // h aliases xr1 (safe)
  float* xl2 = xl1;                                    // reuse dead xl1
  float* xr2 = xl1 + (size_t)N_NODES * NCLS;

  const int nthr = 256;
  // ---- CSR by dst (shared by both layers) ----
  k_zero_int<<<(N_NODES + nthr - 1) / nthr, nthr, 0, stream>>>(cursor, N_NODES);
  k_hist<<<(ET + nthr - 1) / nthr, nthr, 0, stream>>>(ei, cursor);
  int nb = (N_NODES + 1023) / 1024;
  k_scan1<<<nb, nthr, 0, stream>>>(cursor, offsets, bsums);
  k_scan2<<<1, nthr, 0, stream>>>(bsums, nb);
  k_scan3<<<(N_NODES + nthr - 1) / nthr, nthr, 0, stream>>>(bsums, offsets);
  k_copy_int<<<(N_NODES + nthr - 1) / nthr, nthr, 0, stream>>>(offsets, cursor, N_NODES);
  k_scatter<<<(ET + nthr - 1) / nthr, nthr, 0, stream>>>(ei, cursor, srcs);

  // ---- layer 1 ----
  dim3 g1((N_NODES + 63) / 64, 8);
  k_gemm1<<<g1, nthr, 0, stream>>>(x, Wl1, Wr1, xl1, xr1);
  k_gat1<<<(N_NODES + 3) / 4, nthr, 0, stream>>>(xl1, xr1, att1, b1, offsets, srcs, hb);

  // ---- layer 2 ----
  k_gemm2<<<(N_NODES + 31) / 32, nthr, 0, stream>>>(hb, Wl2, Wr2, xl2, xr2);
  k_gat2<<<(N_NODES + 3) / 4, nthr, 0, stream>>>(xl2, xr2, att2, b2, offsets, srcs, out);
}

// Round 2
// 487.918 us; speedup vs baseline: 1.2165x; 1.2165x over previous
//
#include <hip/hip_runtime.h>
#include <hip/hip_bf16.h>

typedef unsigned short u16;
typedef unsigned int u32;
typedef short bf16x8 __attribute__((ext_vector_type(8)));
typedef float f32x4 __attribute__((ext_vector_type(4)));

constexpr int N_NODES = 50000;
constexpr int N_EDGES = 800000;
constexpr int ET      = N_EDGES + N_NODES;   // edges incl. self loops
constexpr int HC      = 256;                 // heads * dim_h (layer 1)
constexpr int NCLS    = 10;
constexpr float NEG   = 0.2f;

__device__ __forceinline__ u16 f2bf(float f) {
  u32 u = __float_as_uint(f);
  u += 0x7fffu + ((u >> 16) & 1u);   // RNE
  return (u16)(u >> 16);
}
__device__ __forceinline__ float bf2f(u16 h) {
  return __uint_as_float(((u32)h) << 16);
}

// ---------------------------- CSR build ----------------------------

__global__ void k_zero_int(int* __restrict__ p, int n) {
  int i = blockIdx.x * 256 + threadIdx.x;
  if (i < n) p[i] = 0;
}

__global__ void k_hist(const int* __restrict__ ei, int* __restrict__ counts) {
  int e = blockIdx.x * 256 + threadIdx.x;
  if (e >= ET) return;
  int d = (e < N_EDGES) ? ei[N_EDGES + e] : (e - N_EDGES);
  atomicAdd(&counts[d], 1);
}

__global__ __launch_bounds__(256) void k_scan1(const int* __restrict__ counts,
                                               int* __restrict__ offsets,
                                               int* __restrict__ bsums) {
  __shared__ int sd[256];
  int t = threadIdx.x;
  int base = blockIdx.x * 1024 + t * 4;
  int v[4];
#pragma unroll
  for (int i = 0; i < 4; ++i) {
    int idx = base + i;
    v[i] = (idx < N_NODES) ? counts[idx] : 0;
  }
  int tsum = v[0] + v[1] + v[2] + v[3];
  sd[t] = tsum;
  __syncthreads();
  for (int off = 1; off < 256; off <<= 1) {
    int x = (t >= off) ? sd[t - off] : 0;
    __syncthreads();
    sd[t] += x;
    __syncthreads();
  }
  int run = sd[t] - tsum;
#pragma unroll
  for (int i = 0; i < 4; ++i) {
    run += v[i];
    int idx = base + i;
    if (idx < N_NODES) offsets[idx + 1] = run;
  }
  if (t == 255) bsums[blockIdx.x] = sd[255];
}

__global__ __launch_bounds__(256) void k_scan2(int* __restrict__ bsums, int nb) {
  __shared__ int sd[256];
  int t = threadIdx.x;
  int v = (t < nb) ? bsums[t] : 0;
  sd[t] = v;
  __syncthreads();
  for (int off = 1; off < 256; off <<= 1) {
    int x = (t >= off) ? sd[t - off] : 0;
    __syncthreads();
    sd[t] += x;
    __syncthreads();
  }
  if (t < nb) bsums[t] = sd[t] - v;  // exclusive
}

__global__ void k_scan3(const int* __restrict__ bsums, int* __restrict__ offsets) {
  int i = blockIdx.x * 256 + threadIdx.x;
  if (i < N_NODES) offsets[i + 1] += bsums[i >> 10];
  if (i == 0) offsets[0] = 0;
}

// scatter using decrementing counts (no cursor copy needed)
__global__ void k_scatter(const int* __restrict__ ei, const int* __restrict__ offsets,
                          int* __restrict__ counts, int* __restrict__ srcs) {
  int e = blockIdx.x * 256 + threadIdx.x;
  if (e >= ET) return;
  int s, d;
  if (e < N_EDGES) { s = ei[e]; d = ei[N_EDGES + e]; }
  else             { s = e - N_EDGES; d = s; }
  int pos = offsets[d] + atomicSub(&counts[d], 1) - 1;
  srcs[pos] = s;
}

// ------------- pack W: Wt[c][k] (c 0..511), split into bf16 hi/lo -----------
__global__ __launch_bounds__(256) void k_packW(const float* __restrict__ Wl,
                                               const float* __restrict__ Wr,
                                               u16* __restrict__ Wt_hi,
                                               u16* __restrict__ Wt_lo) {
  int c = blockIdx.x;       // 0..511
  int k = threadIdx.x;      // 0..255
  float w = (c < 256) ? Wl[k * 256 + c] : Wr[k * 256 + (c - 256)];
  u16 h = f2bf(w);
  float lo = w - bf2f(h);
  Wt_hi[c * 256 + k] = h;
  Wt_lo[c * 256 + k] = f2bf(lo);
}

// --------- layer-1 GEMM via bf16 MFMA, split-precision (3 products) ---------
// C = x @ W  with x split to hi/lo bf16 on the fly; W pre-split (Wt_hi/Wt_lo,
// layout [col][k]).  BM=128, BN=256, BK=32.  grid (391, 2): y=0 -> xl (Wl),
// y=1 -> xr (Wr).  4 waves, each computes a 64x128 sub-tile (4x8 MFMA tiles).
// LDS rows padded to 80B so stride-64B fragment reads are 2-way (free).
__global__ __launch_bounds__(256) void k_gemm1_mfma(const float* __restrict__ x,
                                                    const u16* __restrict__ Wt_hi,
                                                    const u16* __restrict__ Wt_lo,
                                                    float* __restrict__ xl,
                                                    float* __restrict__ xr) {
  __shared__ char smem[61440];
  char* Ah = smem;               // 128 rows * 80B
  char* Al = smem + 10240;
  char* Bh = smem + 20480;       // 256 cols * 80B
  char* Bl = smem + 40960;

  int t = threadIdx.x;
  int lane = t & 63, wave = t >> 6;
  int wm = wave >> 1, wn = wave & 1;
  int row0 = blockIdx.x * 128;
  int bc = blockIdx.y;           // 0 -> Wl/xl, 1 -> Wr/xr
  int col0 = bc * 256;

  f32x4 acc[4][8];
#pragma unroll
  for (int m = 0; m < 4; ++m)
#pragma unroll
    for (int n = 0; n < 8; ++n) acc[m][n] = (f32x4){0.f, 0.f, 0.f, 0.f};

  int ar = t >> 3;    // 0..31 : A row (plus 32*i)
  int ak4 = t & 7;    // float4 index within the 32-k slab
  int rr = lane & 15, kb = lane >> 4;

#pragma unroll 1
  for (int kk = 0; kk < 256; kk += 32) {
    // ---- stage A: read fp32, split to bf16 hi/lo in-register ----
#pragma unroll
    for (int i = 0; i < 4; ++i) {
      int r = ar + 32 * i;
      int grow = row0 + r;
      if (grow >= N_NODES) grow = N_NODES - 1;  // clamp; junk rows never stored
      float4 v = *(const float4*)&x[(size_t)grow * 256 + kk + ak4 * 4];
      u16 h0 = f2bf(v.x), h1 = f2bf(v.y), h2 = f2bf(v.z), h3 = f2bf(v.w);
      u16 l0 = f2bf(v.x - bf2f(h0)), l1 = f2bf(v.y - bf2f(h1));
      u16 l2 = f2bf(v.z - bf2f(h2)), l3 = f2bf(v.w - bf2f(h3));
      uint2 hp = make_uint2((u32)h0 | ((u32)h1 << 16), (u32)h2 | ((u32)h3 << 16));
      uint2 lp = make_uint2((u32)l0 | ((u32)l1 << 16), (u32)l2 | ((u32)l3 << 16));
      int boff = r * 80 + ak4 * 8;
      *(uint2*)(Ah + boff) = hp;
      *(uint2*)(Al + boff) = lp;
    }
    // ---- stage B: copy pre-split W (one col per thread, 32 k = 64B) ----
    {
      const u16* sh = &Wt_hi[(size_t)(col0 + t) * 256 + kk];
      const u16* sl = &Wt_lo[(size_t)(col0 + t) * 256 + kk];
#pragma unroll
      for (int j = 0; j < 4; ++j) {
        *(uint4*)(Bh + t * 80 + j * 16) = *(const uint4*)&sh[j * 8];
        *(uint4*)(Bl + t * 80 + j * 16) = *(const uint4*)&sl[j * 8];
      }
    }
    __syncthreads();
    // ---- fragments + MFMA ----
    bf16x8 a_h[4], a_l[4];
#pragma unroll
    for (int m = 0; m < 4; ++m) {
      int off = (wm * 64 + m * 16 + rr) * 80 + kb * 16;
      a_h[m] = *(const bf16x8*)(Ah + off);
      a_l[m] = *(const bf16x8*)(Al + off);
    }
#pragma unroll
    for (int n = 0; n < 8; ++n) {
      int off = (wn * 128 + n * 16 + rr) * 80 + kb * 16;
      bf16x8 b_h = *(const bf16x8*)(Bh + off);
      bf16x8 b_l = *(const bf16x8*)(Bl + off);
#pragma unroll
      for (int m = 0; m < 4; ++m) {
        acc[m][n] = __builtin_amdgcn_mfma_f32_16x16x32_bf16(a_h[m], b_h, acc[m][n], 0, 0, 0);
        acc[m][n] = __builtin_amdgcn_mfma_f32_16x16x32_bf16(a_l[m], b_h, acc[m][n], 0, 0, 0);
        acc[m][n] = __builtin_amdgcn_mfma_f32_16x16x32_bf16(a_h[m], b_l, acc[m][n], 0, 0, 0);
      }
    }
    __syncthreads();
  }
  // ---- epilogue: C/D layout col=lane&15, row=(lane>>4)*4+reg ----
  float* Cout = bc ? xr : xl;
  int r0w = row0 + wm * 64 + (lane >> 4) * 4;
  int c0w = wn * 128 + (lane & 15);
#pragma unroll
  for (int m = 0; m < 4; ++m)
#pragma unroll
    for (int j = 0; j < 4; ++j) {
      int grow = r0w + m * 16 + j;
      if (grow < N_NODES) {
#pragma unroll
        for (int n = 0; n < 8; ++n)
          Cout[(size_t)grow * 256 + c0w + n * 16] = acc[m][n][j];
      }
    }
}

// ---------------- layer-1 online-softmax aggregation --------------------
__global__ __launch_bounds__(256) void k_gat1(const float* __restrict__ xl,
                                              const float* __restrict__ xr,
                                              const float* __restrict__ att,
                                              const float* __restrict__ b1,
                                              const int* __restrict__ offsets,
                                              const int* __restrict__ srcs,
                                              float* __restrict__ hout) {
  int wave = threadIdx.x >> 6;
  int lane = threadIdx.x & 63;
  int n = blockIdx.x * 4 + wave;
  if (n >= N_NODES) return;
  int c0 = lane * 4;
  float4 attv = *(const float4*)&att[c0];
  float4 xrv  = *(const float4*)&xr[(size_t)n * 256 + c0];
  float m = -__builtin_inff();
  float denom = 0.f;
  float a0 = 0.f, a1 = 0.f, a2 = 0.f, a3 = 0.f;
  int jb = offsets[n], je = offsets[n + 1];
  for (int j = jb; j < je; ++j) {
    int s = srcs[j];
    float4 xlv = *(const float4*)&xl[(size_t)s * 256 + c0];
    float e0 = xlv.x + xrv.x; e0 = e0 > 0.f ? e0 : NEG * e0;
    float e1 = xlv.y + xrv.y; e1 = e1 > 0.f ? e1 : NEG * e1;
    float e2 = xlv.z + xrv.z; e2 = e2 > 0.f ? e2 : NEG * e2;
    float e3 = xlv.w + xrv.w; e3 = e3 > 0.f ? e3 : NEG * e3;
    float p = attv.x * e0 + attv.y * e1 + attv.z * e2 + attv.w * e3;
    p += __shfl_xor(p, 1);
    p += __shfl_xor(p, 2);
    p += __shfl_xor(p, 4);
    p += __shfl_xor(p, 8);
    float mn = fmaxf(m, p);
    float corr = __expf(m - mn);
    float w    = __expf(p - mn);
    denom = denom * corr + w;
    a0 = a0 * corr + w * xlv.x;
    a1 = a1 * corr + w * xlv.y;
    a2 = a2 * corr + w * xlv.z;
    a3 = a3 * corr + w * xlv.w;
    m = mn;
  }
  float inv = 1.0f / denom;
  float4 bv = *(const float4*)&b1[c0];
  float4 o;
  o.x = fmaxf(a0 * inv + bv.x, 0.f);
  o.y = fmaxf(a1 * inv + bv.y, 0.f);
  o.z = fmaxf(a2 * inv + bv.z, 0.f);
  o.w = fmaxf(a3 * inv + bv.w, 0.f);
  *(float4*)&hout[(size_t)n * 256 + c0] = o;
}

// ------------- layer-2 GEMM: xl2 = h@Wl2, xr2 = h@Wr2 ([256,10] each) -------
__global__ __launch_bounds__(256) void k_gemm2(const float* __restrict__ h,
                                               const float* __restrict__ Wl,
                                               const float* __restrict__ Wr,
                                               float* __restrict__ xl2,
                                               float* __restrict__ xr2) {
  __shared__ float Ws[256 * 20];
  __shared__ float hs[32][256];
  int t = threadIdx.x;
  for (int i = t; i < 256 * 10; i += 256) {
    int kk = i / 10, c = i % 10;
    Ws[kk * 20 + c]      = Wl[i];
    Ws[kk * 20 + 10 + c] = Wr[i];
  }
  int row0 = blockIdx.x * 32;
  for (int i = t * 4; i < 32 * 256; i += 256 * 4) {
    int r = i >> 8, c = i & 255;
    int gr = row0 + r;
    float4 v = (gr < N_NODES) ? *(const float4*)&h[(size_t)gr * 256 + c]
                              : make_float4(0.f, 0.f, 0.f, 0.f);
    *(float4*)&hs[r][c] = v;
  }
  __syncthreads();
  int c = t & 31;
  int rbase = t >> 5;
  if (c < 20) {
#pragma unroll
    for (int it = 0; it < 4; ++it) {
      int r = rbase + it * 8;
      int gr = row0 + r;
      if (gr < N_NODES) {
        float acc = 0.f;
#pragma unroll 8
        for (int k = 0; k < 256; ++k) acc += hs[r][k] * Ws[k * 20 + c];
        if (c < 10) xl2[gr * 10 + c] = acc;
        else        xr2[gr * 10 + (c - 10)] = acc;
      }
    }
  }
}

// ---------------- layer-2 aggregation: 4 edge-groups of 16 lanes ------------
__global__ __launch_bounds__(256) void k_gat2(const float* __restrict__ xl2,
                                              const float* __restrict__ xr2,
                                              const float* __restrict__ att2,
                                              const float* __restrict__ b2,
                                              const int* __restrict__ offsets,
                                              const int* __restrict__ srcs,
                                              float* __restrict__ out) {
  int wave = threadIdx.x >> 6;
  int lane = threadIdx.x & 63;
  int n = blockIdx.x * 4 + wave;
  if (n >= N_NODES) return;
  int g = lane >> 4;
  int k = lane & 15;
  bool act = k < NCLS;
  float attk = act ? att2[k] : 0.f;
  float xrk  = act ? xr2[n * NCLS + k] : 0.f;
  float m = -__builtin_inff();
  float denom = 0.f, acc = 0.f;
  int jb = offsets[n], je = offsets[n + 1];
  for (int j = jb + g; j < je; j += 4) {
    int s = srcs[j];
    float xlv = act ? xl2[s * NCLS + k] : 0.f;
    float e = xlv + xrk; e = e > 0.f ? e : NEG * e;
    float p = attk * e;
    p += __shfl_xor(p, 1);
    p += __shfl_xor(p, 2);
    p += __shfl_xor(p, 4);
    p += __shfl_xor(p, 8);
    float mn = fmaxf(m, p);
    float corr = __expf(m - mn);
    float w    = __expf(p - mn);
    denom = denom * corr + w;
    acc   = acc * corr + w * xlv;
    m = mn;
  }
  float mg = fmaxf(m, __shfl_xor(m, 16));
  mg = fmaxf(mg, __shfl_xor(mg, 32));
  float f = __expf(m - mg);
  float d = denom * f;
  d += __shfl_xor(d, 16);
  d += __shfl_xor(d, 32);
  float a = acc * f;
  a += __shfl_xor(a, 16);
  a += __shfl_xor(a, 32);
  if (act && g == 0) out[n * NCLS + k] = a / d + b2[k];
}

// ----------------------------------------------------------------------------

extern "C" void kernel_launch(void* const* d_in, const int* in_sizes, int n_in,
                              void* d_out, int out_size, void* d_ws, size_t ws_size,
                              hipStream_t stream) {
  const float* x    = (const float*)d_in[0];
  const int*   ei   = (const int*)d_in[1];
  const float* Wl1  = (const float*)d_in[2];
  const float* Wr1  = (const float*)d_in[3];
  const float* att1 = (const float*)d_in[4];
  const float* b1   = (const float*)d_in[5];
  const float* Wl2  = (const float*)d_in[6];
  const float* Wr2  = (const float*)d_in[7];
  const float* att2 = (const float*)d_in[8];
  const float* b2   = (const float*)d_in[9];
  float* out = (float*)d_out;

  int* offsets = (int*)d_ws;                 // N+1
  int* counts  = offsets + (N_NODES + 1);    // N
  int* bsums   = counts + N_NODES;           // 256
  int* srcs    = bsums + 256;                // ET
  size_t int_count = (size_t)(N_NODES + 1) + N_NODES + 256 + ET;
  size_t foff = (int_count + 63) & ~(size_t)63;
  float* xl1 = (float*)d_ws + foff;                    // N*256
  float* xr1 = xl1 + (size_t)N_NODES * HC;             // N*256
  u16* Wt_hi = (u16*)(xr1 + (size_t)N_NODES * HC);     // 512*256
  u16* Wt_lo = Wt_hi + 512 * 256;                      // 512*256
  float* hb  = xr1;                                    // h aliases xr1 (safe)
  float* xl2 = xl1;                                    // reuse dead xl1
  float* xr2 = xl1 + (size_t)N_NODES * NCLS;

  const int nthr = 256;
  // ---- CSR by dst (shared by both layers) ----
  k_zero_int<<<(N_NODES + nthr - 1) / nthr, nthr, 0, stream>>>(counts, N_NODES);
  k_hist<<<(ET + nthr - 1) / nthr, nthr, 0, stream>>>(ei, counts);
  int nb = (N_NODES + 1023) / 1024;
  k_scan1<<<nb, nthr, 0, stream>>>(counts, offsets, bsums);
  k_scan2<<<1, nthr, 0, stream>>>(bsums, nb);
  k_scan3<<<(N_NODES + nthr - 1) / nthr, nthr, 0, stream>>>(bsums, offsets);
  k_scatter<<<(ET + nthr - 1) / nthr, nthr, 0, stream>>>(ei, offsets, counts, srcs);

  // ---- layer 1 ----
  k_packW<<<512, nthr, 0, stream>>>(Wl1, Wr1, Wt_hi, Wt_lo);
  dim3 g1((N_NODES + 127) / 128, 2);
  k_gemm1_mfma<<<g1, nthr, 0, stream>>>(x, Wt_hi, Wt_lo, xl1, xr1);
  k_gat1<<<(N_NODES + 3) / 4, nthr, 0, stream>>>(xl1, xr1, att1, b1, offsets, srcs, hb);

  // ---- layer 2 ----
  k_gemm2<<<(N_NODES + 31) / 32, nthr, 0, stream>>>(hb, Wl2, Wr2, xl2, xr2);
  k_gat2<<<(N_NODES + 3) / 4, nthr, 0, stream>>>(xl2, xr2, att2, b2, offsets, srcs, out);
}

// Round 4
// 424.004 us; speedup vs baseline: 1.3999x; 1.1507x over previous
//
#include <hip/hip_runtime.h>
#include <hip/hip_bf16.h>

typedef unsigned short u16;
typedef unsigned int u32;
typedef short bf16x8 __attribute__((ext_vector_type(8)));
typedef float f32x4 __attribute__((ext_vector_type(4)));

constexpr int N_NODES = 50000;
constexpr int N_EDGES = 800000;
constexpr int ET      = N_EDGES + N_NODES;   // edges incl. self loops
constexpr int HC      = 256;                 // heads * dim_h (layer 1)
constexpr int NCLS    = 10;
constexpr float NEG   = 0.2f;

__device__ __forceinline__ u16 f2bf(float f) {
  u32 u = __float_as_uint(f);
  u += 0x7fffu + ((u >> 16) & 1u);   // RNE
  return (u16)(u >> 16);
}
__device__ __forceinline__ float bf2f(u16 h) {
  return __uint_as_float(((u32)h) << 16);
}

// DPP row_ror helpers: 16-lane circulant all-reduce (VALU pipe, no lgkm dep)
__device__ __forceinline__ float dpp_ror8(float v) {
  return __uint_as_float(__builtin_amdgcn_mov_dpp(__float_as_uint(v), 0x128, 0xf, 0xf, true));
}
__device__ __forceinline__ float dpp_ror4(float v) {
  return __uint_as_float(__builtin_amdgcn_mov_dpp(__float_as_uint(v), 0x124, 0xf, 0xf, true));
}
__device__ __forceinline__ float dpp_ror2(float v) {
  return __uint_as_float(__builtin_amdgcn_mov_dpp(__float_as_uint(v), 0x122, 0xf, 0xf, true));
}
__device__ __forceinline__ float dpp_ror1(float v) {
  return __uint_as_float(__builtin_amdgcn_mov_dpp(__float_as_uint(v), 0x121, 0xf, 0xf, true));
}
// sum over the 16-lane row; every lane gets the total
__device__ __forceinline__ float row16_allsum(float p) {
  p += dpp_ror8(p);
  p += dpp_ror4(p);
  p += dpp_ror2(p);
  p += dpp_ror1(p);
  return p;
}

// ---------------------------- CSR build ----------------------------

__global__ void k_zero_int(int* __restrict__ p, int n) {
  int i = blockIdx.x * 256 + threadIdx.x;
  if (i < n) p[i] = 0;
}

__global__ void k_hist(const int* __restrict__ ei, int* __restrict__ counts) {
  int e = blockIdx.x * 256 + threadIdx.x;
  if (e >= ET) return;
  int d = (e < N_EDGES) ? ei[N_EDGES + e] : (e - N_EDGES);
  atomicAdd(&counts[d], 1);
}

__global__ __launch_bounds__(256) void k_scan1(const int* __restrict__ counts,
                                               int* __restrict__ offsets,
                                               int* __restrict__ bsums) {
  __shared__ int sd[256];
  int t = threadIdx.x;
  int base = blockIdx.x * 1024 + t * 4;
  int v[4];
#pragma unroll
  for (int i = 0; i < 4; ++i) {
    int idx = base + i;
    v[i] = (idx < N_NODES) ? counts[idx] : 0;
  }
  int tsum = v[0] + v[1] + v[2] + v[3];
  sd[t] = tsum;
  __syncthreads();
  for (int off = 1; off < 256; off <<= 1) {
    int x = (t >= off) ? sd[t - off] : 0;
    __syncthreads();
    sd[t] += x;
    __syncthreads();
  }
  int run = sd[t] - tsum;
#pragma unroll
  for (int i = 0; i < 4; ++i) {
    run += v[i];
    int idx = base + i;
    if (idx < N_NODES) offsets[idx + 1] = run;
  }
  if (t == 255) bsums[blockIdx.x] = sd[255];
}

__global__ __launch_bounds__(256) void k_scan2(int* __restrict__ bsums, int nb) {
  __shared__ int sd[256];
  int t = threadIdx.x;
  int v = (t < nb) ? bsums[t] : 0;
  sd[t] = v;
  __syncthreads();
  for (int off = 1; off < 256; off <<= 1) {
    int x = (t >= off) ? sd[t - off] : 0;
    __syncthreads();
    sd[t] += x;
    __syncthreads();
  }
  if (t < nb) bsums[t] = sd[t] - v;  // exclusive
}

__global__ void k_scan3(const int* __restrict__ bsums, int* __restrict__ offsets) {
  int i = blockIdx.x * 256 + threadIdx.x;
  if (i < N_NODES) offsets[i + 1] += bsums[i >> 10];
  if (i == 0) offsets[0] = 0;
}

__global__ void k_scatter(const int* __restrict__ ei, const int* __restrict__ offsets,
                          int* __restrict__ counts, int* __restrict__ srcs) {
  int e = blockIdx.x * 256 + threadIdx.x;
  if (e >= ET) return;
  int s, d;
  if (e < N_EDGES) { s = ei[e]; d = ei[N_EDGES + e]; }
  else             { s = e - N_EDGES; d = s; }
  int pos = offsets[d] + atomicSub(&counts[d], 1) - 1;
  srcs[pos] = s;
}

// ------------- pack W: Wt[c][k] (c 0..511), split into bf16 hi/lo -----------
__global__ __launch_bounds__(256) void k_packW(const float* __restrict__ Wl,
                                               const float* __restrict__ Wr,
                                               u16* __restrict__ Wt_hi,
                                               u16* __restrict__ Wt_lo) {
  int c = blockIdx.x;       // 0..511
  int k = threadIdx.x;      // 0..255
  float w = (c < 256) ? Wl[k * 256 + c] : Wr[k * 256 + (c - 256)];
  u16 h = f2bf(w);
  float lo = w - bf2f(h);
  Wt_hi[c * 256 + k] = h;
  Wt_lo[c * 256 + k] = f2bf(lo);
}

// --------- layer-1 GEMM via bf16 MFMA, split-precision (3 products) ---------
__global__ __launch_bounds__(256) void k_gemm1_mfma(const float* __restrict__ x,
                                                    const u16* __restrict__ Wt_hi,
                                                    const u16* __restrict__ Wt_lo,
                                                    float* __restrict__ xl,
                                                    float* __restrict__ xr) {
  __shared__ char smem[61440];
  char* Ah = smem;               // 128 rows * 80B
  char* Al = smem + 10240;
  char* Bh = smem + 20480;       // 256 cols * 80B
  char* Bl = smem + 40960;

  int t = threadIdx.x;
  int lane = t & 63, wave = t >> 6;
  int wm = wave >> 1, wn = wave & 1;
  int row0 = blockIdx.x * 128;
  int bc = blockIdx.y;           // 0 -> Wl/xl, 1 -> Wr/xr
  int col0 = bc * 256;

  f32x4 acc[4][8];
#pragma unroll
  for (int m = 0; m < 4; ++m)
#pragma unroll
    for (int n = 0; n < 8; ++n) acc[m][n] = (f32x4){0.f, 0.f, 0.f, 0.f};

  int ar = t >> 3;
  int ak4 = t & 7;
  int rr = lane & 15, kb = lane >> 4;

#pragma unroll 1
  for (int kk = 0; kk < 256; kk += 32) {
#pragma unroll
    for (int i = 0; i < 4; ++i) {
      int r = ar + 32 * i;
      int grow = row0 + r;
      if (grow >= N_NODES) grow = N_NODES - 1;
      float4 v = *(const float4*)&x[(size_t)grow * 256 + kk + ak4 * 4];
      u16 h0 = f2bf(v.x), h1 = f2bf(v.y), h2 = f2bf(v.z), h3 = f2bf(v.w);
      u16 l0 = f2bf(v.x - bf2f(h0)), l1 = f2bf(v.y - bf2f(h1));
      u16 l2 = f2bf(v.z - bf2f(h2)), l3 = f2bf(v.w - bf2f(h3));
      uint2 hp = make_uint2((u32)h0 | ((u32)h1 << 16), (u32)h2 | ((u32)h3 << 16));
      uint2 lp = make_uint2((u32)l0 | ((u32)l1 << 16), (u32)l2 | ((u32)l3 << 16));
      int boff = r * 80 + ak4 * 8;
      *(uint2*)(Ah + boff) = hp;
      *(uint2*)(Al + boff) = lp;
    }
    {
      const u16* sh = &Wt_hi[(size_t)(col0 + t) * 256 + kk];
      const u16* sl = &Wt_lo[(size_t)(col0 + t) * 256 + kk];
#pragma unroll
      for (int j = 0; j < 4; ++j) {
        *(uint4*)(Bh + t * 80 + j * 16) = *(const uint4*)&sh[j * 8];
        *(uint4*)(Bl + t * 80 + j * 16) = *(const uint4*)&sl[j * 8];
      }
    }
    __syncthreads();
    bf16x8 a_h[4], a_l[4];
#pragma unroll
    for (int m = 0; m < 4; ++m) {
      int off = (wm * 64 + m * 16 + rr) * 80 + kb * 16;
      a_h[m] = *(const bf16x8*)(Ah + off);
      a_l[m] = *(const bf16x8*)(Al + off);
    }
#pragma unroll
    for (int n = 0; n < 8; ++n) {
      int off = (wn * 128 + n * 16 + rr) * 80 + kb * 16;
      bf16x8 b_h = *(const bf16x8*)(Bh + off);
      bf16x8 b_l = *(const bf16x8*)(Bl + off);
#pragma unroll
      for (int m = 0; m < 4; ++m) {
        acc[m][n] = __builtin_amdgcn_mfma_f32_16x16x32_bf16(a_h[m], b_h, acc[m][n], 0, 0, 0);
        acc[m][n] = __builtin_amdgcn_mfma_f32_16x16x32_bf16(a_l[m], b_h, acc[m][n], 0, 0, 0);
        acc[m][n] = __builtin_amdgcn_mfma_f32_16x16x32_bf16(a_h[m], b_l, acc[m][n], 0, 0, 0);
      }
    }
    __syncthreads();
  }
  float* Cout = bc ? xr : xl;
  int r0w = row0 + wm * 64 + (lane >> 4) * 4;
  int c0w = wn * 128 + (lane & 15);
#pragma unroll
  for (int m = 0; m < 4; ++m)
#pragma unroll
    for (int j = 0; j < 4; ++j) {
      int grow = r0w + m * 16 + j;
      if (grow < N_NODES) {
#pragma unroll
        for (int n = 0; n < 8; ++n)
          Cout[(size_t)grow * 256 + c0w + n * 16] = acc[m][n][j];
      }
    }
}

// ---- layer-1 aggregation (4-chain ILP) + fused layer-2 GEMM epilogue -------
// one wave per dst node; lane owns channels 4l..4l+3 (head = lane>>4).
// 4 independent online-softmax chains over edges j,j+1,j+2,j+3; flash-merge.
// Epilogue computes xl2[n] = h@Wl2, xr2[n] = h@Wr2 (h never materialized).
__global__ __launch_bounds__(256) void k_gat1_fused(
    const float* __restrict__ xl, const float* __restrict__ xr,
    const float* __restrict__ att, const float* __restrict__ b1,
    const float* __restrict__ Wl2, const float* __restrict__ Wr2,
    const int* __restrict__ offsets, const int* __restrict__ srcs,
    float* __restrict__ xl2, float* __restrict__ xr2) {
  __shared__ float Ws[20][256];   // W2 transposed: Ws[c][k]; c<10 Wl2, c>=10 Wr2
  int t = threadIdx.x;
#pragma unroll
  for (int c = 0; c < 10; ++c) {
    Ws[c][t]      = Wl2[t * 10 + c];
    Ws[c + 10][t] = Wr2[t * 10 + c];
  }
  __syncthreads();

  int wave = t >> 6, lane = t & 63;
  int n = blockIdx.x * 4 + wave;           // grid is exactly N/4
  int c0 = lane * 4;
  float4 attv = *(const float4*)&att[c0];
  float4 xrv  = *(const float4*)&xr[(size_t)n * 256 + c0];

  float m0 = -1e30f, m1 = -1e30f, m2 = -1e30f, m3 = -1e30f;
  float d0 = 0.f, d1 = 0.f, d2 = 0.f, d3 = 0.f;
  float4 A0 = {0,0,0,0}, A1 = {0,0,0,0}, A2 = {0,0,0,0}, A3 = {0,0,0,0};

  auto proc = [&](float4 xv, float& m, float& d, float4& A) {
    float e0 = xv.x + xrv.x; e0 = fmaxf(e0, NEG * e0);
    float e1 = xv.y + xrv.y; e1 = fmaxf(e1, NEG * e1);
    float e2 = xv.z + xrv.z; e2 = fmaxf(e2, NEG * e2);
    float e3 = xv.w + xrv.w; e3 = fmaxf(e3, NEG * e3);
    float p = attv.x * e0 + attv.y * e1 + attv.z * e2 + attv.w * e3;
    p = row16_allsum(p);                       // per-head score
    float mn = fmaxf(m, p);
    float corr = __expf(m - mn);
    float w    = __expf(p - mn);
    d = d * corr + w;
    A.x = A.x * corr + w * xv.x;
    A.y = A.y * corr + w * xv.y;
    A.z = A.z * corr + w * xv.z;
    A.w = A.w * corr + w * xv.w;
    m = mn;
  };

  int jb = offsets[n], je = offsets[n + 1];
  int j = jb;
  for (; j + 4 <= je; j += 4) {
    int s0 = srcs[j], s1 = srcs[j + 1], s2 = srcs[j + 2], s3 = srcs[j + 3];
    float4 x0 = *(const float4*)&xl[(size_t)s0 * 256 + c0];
    float4 x1 = *(const float4*)&xl[(size_t)s1 * 256 + c0];
    float4 x2 = *(const float4*)&xl[(size_t)s2 * 256 + c0];
    float4 x3 = *(const float4*)&xl[(size_t)s3 * 256 + c0];
    proc(x0, m0, d0, A0);
    proc(x1, m1, d1, A1);
    proc(x2, m2, d2, A2);
    proc(x3, m3, d3, A3);
  }
  for (; j < je; ++j) {
    int s = srcs[j];
    float4 xv = *(const float4*)&xl[(size_t)s * 256 + c0];
    proc(xv, m0, d0, A0);
  }

  auto merge = [](float& ma, float& da, float4& Aa, float mb, float db, float4 Ab) {
    float mm = fmaxf(ma, mb);
    float fa = __expf(ma - mm), fb = __expf(mb - mm);
    da = da * fa + db * fb;
    Aa.x = Aa.x * fa + Ab.x * fb;
    Aa.y = Aa.y * fa + Ab.y * fb;
    Aa.z = Aa.z * fa + Ab.z * fb;
    Aa.w = Aa.w * fa + Ab.w * fb;
    ma = mm;
  };
  merge(m0, d0, A0, m1, d1, A1);
  merge(m2, d2, A2, m3, d3, A3);
  merge(m0, d0, A0, m2, d2, A2);

  float inv = 1.0f / d0;
  float4 bv = *(const float4*)&b1[c0];
  float4 ov;
  ov.x = fmaxf(A0.x * inv + bv.x, 0.f);
  ov.y = fmaxf(A0.y * inv + bv.y, 0.f);
  ov.z = fmaxf(A0.z * inv + bv.z, 0.f);
  ov.w = fmaxf(A0.w * inv + bv.w, 0.f);

  // ---- fused layer-2 transform: p[c] = sum_k h[k] * W2[k][c] ----
  float p[20];
#pragma unroll
  for (int c = 0; c < 20; ++c) {
    float4 w4 = *(const float4*)&Ws[c][c0];
    p[c] = ov.x * w4.x + ov.y * w4.y + ov.z * w4.z + ov.w * w4.w;
  }
#pragma unroll
  for (int c = 0; c < 20; ++c) {
    p[c] = row16_allsum(p[c]);           // 16-lane groups via DPP
    p[c] += __shfl_xor(p[c], 16);
    p[c] += __shfl_xor(p[c], 32);
  }
  if (lane == 0) {
#pragma unroll
    for (int c = 0; c < 10; ++c) xl2[n * NCLS + c] = p[c];
#pragma unroll
    for (int c = 0; c < 10; ++c) xr2[n * NCLS + c] = p[c + 10];
  }
}

// ---------------- layer-2 aggregation: 4 edge-groups of 16 lanes ------------
__global__ __launch_bounds__(256) void k_gat2(const float* __restrict__ xl2,
                                              const float* __restrict__ xr2,
                                              const float* __restrict__ att2,
                                              const float* __restrict__ b2,
                                              const int* __restrict__ offsets,
                                              const int* __restrict__ srcs,
                                              float* __restrict__ out) {
  int wave = threadIdx.x >> 6;
  int lane = threadIdx.x & 63;
  int n = blockIdx.x * 4 + wave;
  if (n >= N_NODES) return;
  int g = lane >> 4;
  int k = lane & 15;
  bool act = k < NCLS;
  float attk = act ? att2[k] : 0.f;
  float xrk  = act ? xr2[n * NCLS + k] : 0.f;
  float m = -1e30f;
  float denom = 0.f, acc = 0.f;
  int jb = offsets[n], je = offsets[n + 1];
  for (int j = jb + g; j < je; j += 4) {
    int s = srcs[j];
    float xlv = act ? xl2[s * NCLS + k] : 0.f;
    float e = xlv + xrk; e = fmaxf(e, NEG * e);
    float p = attk * e;
    p = row16_allsum(p);
    float mn = fmaxf(m, p);
    float corr = __expf(m - mn);
    float w    = __expf(p - mn);
    denom = denom * corr + w;
    acc   = acc * corr + w * xlv;
    m = mn;
  }
  float mg = fmaxf(m, __shfl_xor(m, 16));
  mg = fmaxf(mg, __shfl_xor(mg, 32));
  float f = __expf(m - mg);
  float d = denom * f;
  d += __shfl_xor(d, 16);
  d += __shfl_xor(d, 32);
  float a = acc * f;
  a += __shfl_xor(a, 16);
  a += __shfl_xor(a, 32);
  if (act && g == 0) out[n * NCLS + k] = a / d + b2[k];
}

// ----------------------------------------------------------------------------

extern "C" void kernel_launch(void* const* d_in, const int* in_sizes, int n_in,
                              void* d_out, int out_size, void* d_ws, size_t ws_size,
                              hipStream_t stream) {
  const float* x    = (const float*)d_in[0];
  const int*   ei   = (const int*)d_in[1];
  const float* Wl1  = (const float*)d_in[2];
  const float* Wr1  = (const float*)d_in[3];
  const float* att1 = (const float*)d_in[4];
  const float* b1   = (const float*)d_in[5];
  const float* Wl2  = (const float*)d_in[6];
  const float* Wr2  = (const float*)d_in[7];
  const float* att2 = (const float*)d_in[8];
  const float* b2   = (const float*)d_in[9];
  float* out = (float*)d_out;

  int* offsets = (int*)d_ws;                 // N+1
  int* counts  = offsets + (N_NODES + 1);    // N
  int* bsums   = counts + N_NODES;           // 256
  int* srcs    = bsums + 256;                // ET
  size_t int_count = (size_t)(N_NODES + 1) + N_NODES + 256 + ET;
  size_t foff = (int_count + 63) & ~(size_t)63;
  float* xl1 = (float*)d_ws + foff;                    // N*256
  float* xr1 = xl1 + (size_t)N_NODES * HC;             // N*256
  u16* Wt_hi = (u16*)(xr1 + (size_t)N_NODES * HC);     // 512*256
  u16* Wt_lo = Wt_hi + 512 * 256;                      // 512*256
  float* xl2 = (float*)(Wt_lo + 512 * 256);            // N*10
  float* xr2 = xl2 + (size_t)N_NODES * NCLS;           // N*10

  const int nthr = 256;
  // ---- CSR by dst (shared by both layers) ----
  k_zero_int<<<(N_NODES + nthr - 1) / nthr, nthr, 0, stream>>>(counts, N_NODES);
  k_hist<<<(ET + nthr - 1) / nthr, nthr, 0, stream>>>(ei, counts);
  int nb = (N_NODES + 1023) / 1024;
  k_scan1<<<nb, nthr, 0, stream>>>(counts, offsets, bsums);
  k_scan2<<<1, nthr, 0, stream>>>(bsums, nb);
  k_scan3<<<(N_NODES + nthr - 1) / nthr, nthr, 0, stream>>>(bsums, offsets);
  k_scatter<<<(ET + nthr - 1) / nthr, nthr, 0, stream>>>(ei, offsets, counts, srcs);

  // ---- layer 1 GEMM ----
  k_packW<<<512, nthr, 0, stream>>>(Wl1, Wr1, Wt_hi, Wt_lo);
  dim3 g1((N_NODES + 127) / 128, 2);
  k_gemm1_mfma<<<g1, nthr, 0, stream>>>(x, Wt_hi, Wt_lo, xl1, xr1);

  // ---- layer-1 aggregate + fused layer-2 GEMM ----
  k_gat1_fused<<<N_NODES / 4, nthr, 0, stream>>>(xl1, xr1, att1, b1, Wl2, Wr2,
                                                 offsets, srcs, xl2, xr2);

  // ---- layer-2 aggregation ----
  k_gat2<<<(N_NODES + 3) / 4, nthr, 0, stream>>>(xl2, xr2, att2, b2, offsets, srcs, out);
}